// Round 5
// baseline (374.827 us; speedup 1.0000x reference)
//
#include <hip/hip_runtime.h>
#include <cstdint>
#include <cstddef>

#define BB   4
#define AA   256
#define NNB  64
#define FF   128
#define NBAS 20
#define NLAY 3
#define BA   (BB*AA)        // 1024 atoms total
#define EDG  (BA*NNB)       // 65536 edges

typedef __attribute__((ext_vector_type(8))) short bf16x8;
typedef __attribute__((ext_vector_type(4))) float f32x4;

__device__ __forceinline__ float silu_f(float x){ return x / (1.0f + __expf(-x)); }

// round-to-nearest-even f32 -> bf16 bits
__device__ __forceinline__ unsigned short f2bf(float x){
  unsigned int u = __float_as_uint(x);
  u += 0x7FFFu + ((u >> 16) & 1u);
  return (unsigned short)(u >> 16);
}
__device__ __forceinline__ unsigned int pk2(float a, float b){
  return (unsigned int)f2bf(a) | ((unsigned int)f2bf(b) << 16);
}

// ---------------- init: inv_node = emb[atomic_numbers] ----------------
__global__ void k_init(const int* __restrict__ z, const float* __restrict__ emb,
                       float* __restrict__ inv_node){
  int id = blockIdx.x*256 + threadIdx.x;
  int atom = id >> 7, o = id & 127;
  inv_node[id] = emb[z[atom]*FF + o];
}

// ---------------- geometry: bf16 rbf [EDG][32] (zero-padded), cutoff, unit ----------------
__global__ void k_geom(const float* __restrict__ dist, const float* __restrict__ dvec,
                       unsigned short* __restrict__ rbf_bf, float* __restrict__ cutw,
                       float* __restrict__ unitv){
  int e = blockIdx.x*256 + threadIdx.x;
  float d = dist[e];
  float x = d * 0.2f;
  float x2 = x*x, x4 = x2*x2, x6 = x4*x2, x7 = x6*x, x8 = x7*x;
  float f = 1.0f - 28.0f*x6 + 48.0f*x7 - 21.0f*x8;
  f = (x < 1.0f) ? f : 0.0f;
  cutw[e] = f;
  float inv = 1.0f/(d + 1e-8f);
  unitv[(size_t)e*3+0] = dvec[(size_t)e*3+0]*inv;
  unitv[(size_t)e*3+1] = dvec[(size_t)e*3+1]*inv;
  unitv[(size_t)e*3+2] = dvec[(size_t)e*3+2]*inv;
  const float c = 0.6283185307179586f;        // pi/5
  unsigned short* rb = rbf_bf + (size_t)e*32;
  #pragma unroll
  for (int n=1;n<=NBAS;++n) rb[n-1] = f2bf(sinf((float)n*c*d)*inv);
  #pragma unroll
  for (int k=NBAS;k<32;++k) rb[k] = 0;
}

// ------------- weight conversion: eqf_W1, eqf_W2, eme_W1, eme_W2 (+ padded me_W) ------------
__global__ void k_cvtw(const float* __restrict__ a, const float* __restrict__ b,
                       const float* __restrict__ c, const float* __restrict__ d,
                       const float* __restrict__ me, unsigned short* __restrict__ out){
  int id = blockIdx.x*256 + threadIdx.x;
  if (id < 196608){
    int reg = id / 49152, off = id - reg*49152;
    const float* src = (reg==0)?a:(reg==1)?b:(reg==2)?c:d;
    out[id] = f2bf(src[off]);
  } else if (id < 196608 + 12288){
    int p = id - 196608;
    int l = p >> 12;            // layer
    int rem = p & 4095;
    int row = rem >> 5, k = rem & 31;
    float v = (k < NBAS) ? me[((size_t)l*FF + row)*NBAS + k] : 0.0f;
    out[id] = f2bf(v);
  }
}

// ---------------- f32 two-pass MLP core over 16 rows (node MLPs) ----------------
__device__ __forceinline__ void mlp16(const float (*xs)[FF], float (*hs)[FF], int o,
    const float* __restrict__ W1, const float* __restrict__ b1,
    const float* __restrict__ W2, const float* __restrict__ b2, float acc[16]){
  #pragma unroll
  for (int r=0;r<16;++r) acc[r] = b1[o];
  #pragma unroll
  for (int ic=0;ic<4;++ic){
    float4 wv[8];
    #pragma unroll
    for (int j=0;j<8;++j) wv[j] = *reinterpret_cast<const float4*>(&W1[(size_t)o*FF + ic*32 + j*4]);
    #pragma unroll
    for (int r=0;r<16;++r){
      #pragma unroll
      for (int j=0;j<8;++j){
        float4 xv = *reinterpret_cast<const float4*>(&xs[r][ic*32+j*4]);
        acc[r] = fmaf(xv.x, wv[j].x, acc[r]);
        acc[r] = fmaf(xv.y, wv[j].y, acc[r]);
        acc[r] = fmaf(xv.z, wv[j].z, acc[r]);
        acc[r] = fmaf(xv.w, wv[j].w, acc[r]);
      }
    }
  }
  #pragma unroll
  for (int r=0;r<16;++r) hs[r][o] = silu_f(acc[r]);
  __syncthreads();
  #pragma unroll
  for (int r=0;r<16;++r) acc[r] = b2[o];
  #pragma unroll
  for (int ic=0;ic<4;++ic){
    float4 wv[8];
    #pragma unroll
    for (int j=0;j<8;++j) wv[j] = *reinterpret_cast<const float4*>(&W2[(size_t)o*FF + ic*32 + j*4]);
    #pragma unroll
    for (int r=0;r<16;++r){
      #pragma unroll
      for (int j=0;j<8;++j){
        float4 xv = *reinterpret_cast<const float4*>(&hs[r][ic*32+j*4]);
        acc[r] = fmaf(xv.x, wv[j].x, acc[r]);
        acc[r] = fmaf(xv.y, wv[j].y, acc[r]);
        acc[r] = fmaf(xv.z, wv[j].z, acc[r]);
        acc[r] = fmaf(xv.w, wv[j].w, acc[r]);
      }
    }
  }
}

// ---------------- three node MLPs in one dispatch (blockIdx.y selects) ----------------
__global__ __launch_bounds__(128) void k_mlp_node3(const float* __restrict__ X,
    const float* W1a, const float* b1a, const float* W2a, const float* b2a, float* Ya,
    const float* W1b, const float* b1b, const float* W2b, const float* b2b, float* Yb,
    const float* W1c, const float* b1c, const float* W2c, const float* b2c, float* Yc){
  const float *W1,*b1,*W2,*b2; float* Y;
  if (blockIdx.y==0){ W1=W1a;b1=b1a;W2=W2a;b2=b2a;Y=Ya; }
  else if (blockIdx.y==1){ W1=W1b;b1=b1b;W2=W2b;b2=b2b;Y=Yb; }
  else { W1=W1c;b1=b1c;W2=W2c;b2=b2c;Y=Yc; }
  __shared__ __align__(16) float xs[16][FF];
  __shared__ __align__(16) float hs[16][FF];
  const int o = threadIdx.x;
  const int row0 = blockIdx.x * 16;
  #pragma unroll
  for (int r=0;r<16;++r) xs[r][o] = X[(size_t)(row0+r)*FF + o];
  __syncthreads();
  float acc[16];
  mlp16(xs, hs, o, W1, b1, W2, b2, acc);
  #pragma unroll
  for (int r=0;r<16;++r) Y[(size_t)(row0+r)*FF + o] = acc[r];
}

// =====================================================================
// Stage kernel: one block = one atom. me-MLP via MFMA (swapped), build
// inv_msg (bf16 -> global, coalesced via LDS), eqmsgF/mask -> scalg,
// eq_F accumulation.
// =====================================================================
__global__ __launch_bounds__(256) void k_stage(
    const unsigned short* __restrict__ rbf_bf,
    const float* __restrict__ cutw, const float* __restrict__ unitv,
    const float* __restrict__ maskp, const int* __restrict__ nbrs,
    const float* __restrict__ msg_node,
    const unsigned short* __restrict__ meWb, const float* __restrict__ meb,
    const float* __restrict__ eqcW,
    unsigned short* __restrict__ inv_msg, float* __restrict__ scalg,
    float* __restrict__ eqF){
  __shared__ unsigned short Hs[64*136];
  __shared__ float eqFred[4][3];
  const int t = threadIdx.x, w = t>>6, l = t&63;
  const int atom = blockIdx.x;
  const int bbase = (atom/AA)*AA;
  const int le = w*16 + (l&15);
  const int eg = atom*NNB + le;
  const int kg = (l>>4)<<3;
  const int r0 = (l>>4)<<2;

  f32x4 acc[8];
  bf16x8 rfr = *(const bf16x8*)(rbf_bf + (size_t)eg*32 + kg);
  #pragma unroll
  for (int nt=0;nt<8;++nt){
    bf16x8 wfr = *(const bf16x8*)(meWb + (nt*16 + (l&15))*32 + kg);
    acc[nt] = __builtin_amdgcn_mfma_f32_16x16x32_bf16(wfr, rfr, f32x4{0.f,0.f,0.f,0.f}, 0,0,0);
  }
  const float ct = cutw[eg];
  const int   nbv = bbase + nbrs[eg];
  float pv = 0.f;
  #pragma unroll
  for (int nt=0;nt<8;++nt){
    int o0 = nt*16 + r0;
    float4 mb = *(const float4*)(meb + o0);
    float4 mi = *(const float4*)(msg_node + (size_t)atom*FF + o0);
    float4 mf = *(const float4*)(msg_node + (size_t)nbv*FF + o0);
    float4 ec = *(const float4*)(eqcW + o0);
    float v0 = (acc[nt][0]+mb.x)*ct*mi.x*mf.x;
    float v1 = (acc[nt][1]+mb.y)*ct*mi.y*mf.y;
    float v2 = (acc[nt][2]+mb.z)*ct*mi.z*mf.z;
    float v3 = (acc[nt][3]+mb.w)*ct*mi.w*mf.w;
    pv = fmaf(v0,ec.x, fmaf(v1,ec.y, fmaf(v2,ec.z, fmaf(v3,ec.w, pv))));
    uint2 u; u.x = pk2(v0,v1); u.y = pk2(v2,v3);
    *(uint2*)(&Hs[le*136 + o0]) = u;
  }
  pv += __shfl_xor(pv,16); pv += __shfl_xor(pv,32);
  float cf0=0.f, cf1=0.f, cf2=0.f;
  if (l < 16){
    float m  = maskp[eg];
    float s0 = pv*unitv[(size_t)eg*3+0];
    float s1 = pv*unitv[(size_t)eg*3+1];
    float s2 = pv*unitv[(size_t)eg*3+2];
    float4 sv; sv.x=s0; sv.y=s1; sv.z=s2; sv.w=m;
    *(float4*)(scalg + (size_t)eg*4) = sv;
    cf0 = s0*m; cf1 = s1*m; cf2 = s2*m;
  }
  #pragma unroll
  for (int s2=1; s2<16; s2<<=1){
    cf0 += __shfl_xor(cf0,s2); cf1 += __shfl_xor(cf1,s2); cf2 += __shfl_xor(cf2,s2);
  }
  if (l == 0){ eqFred[w][0]=cf0; eqFred[w][1]=cf1; eqFred[w][2]=cf2; }
  __syncthreads();
  unsigned short* og = inv_msg + (size_t)atom*NNB*FF;
  #pragma unroll
  for (int c=t; c<1024; c+=256){
    int row = c >> 4, ko = (c & 15) << 3;
    *(int4*)(og + row*FF + ko) = *(const int4*)(&Hs[row*136 + ko]);
  }
  if (t < 3) eqF[atom*3+t] += eqFred[0][t]+eqFred[1][t]+eqFred[2][t]+eqFred[3][t];
}

// =====================================================================
// Merged edge-MLP kernel: one block = one atom, eqf AND eme paths.
// X fragments loaded ONCE; GEMM1-eqf -> Hs1, GEMM1-eme -> Hs2 (swapped,
// packed uint2 writes); barrier; GEMM2s (unswapped) + epilogues; barrier;
// final writes. eme gather uses transposed eqdrT[atom][f][4] -> float4.
// =====================================================================
__global__ __launch_bounds__(256) void k_edge2(
    const unsigned short* __restrict__ inv_msg,
    const unsigned short* __restrict__ W1eq, const float* __restrict__ b1eq,
    const unsigned short* __restrict__ W2eq, const float* __restrict__ b2eq,
    const unsigned short* __restrict__ W1me, const unsigned short* __restrict__ W2me,
    const float* __restrict__ scalg, const float* __restrict__ maskp,
    const int* __restrict__ nbrs, const float* __restrict__ eqdrT,
    float* __restrict__ eqf_out, float* __restrict__ updf,
    float* __restrict__ upddr){
  __shared__ unsigned short Hs1[64*136];
  __shared__ unsigned short Hs2[64*136];
  __shared__ float scal[64][4];
  __shared__ int   nbq[64];
  __shared__ float afl1[4][384];
  __shared__ float afl2[4][384];
  const int t = threadIdx.x, w = t>>6, l = t&63;
  const int atom = blockIdx.x;
  const int le = w*16 + (l&15);
  const int kg = (l>>4)<<3;
  const int r0 = (l>>4)<<2;

  if (t < 64){
    float4 s = *(const float4*)(scalg + (size_t)(atom*NNB + t)*4);
    scal[t][0]=s.x; scal[t][1]=s.y; scal[t][2]=s.z; scal[t][3]=s.w;
    nbq[t] = (atom/AA)*AA + nbrs[atom*NNB + t];
  }

  // X fragments from global inv_msg (loaded once, used by both GEMM1s)
  bf16x8 xfrag[4];
  #pragma unroll
  for (int ks=0;ks<4;++ks)
    xfrag[ks] = *(const bf16x8*)(inv_msg + ((size_t)atom*NNB + le)*FF + ks*32 + kg);

  f32x4 acc[8];
  // ---------------- GEMM1 eqf (swapped) -> Hs1 ----------------
  #pragma unroll
  for (int nt=0;nt<8;++nt) acc[nt] = f32x4{0.f,0.f,0.f,0.f};
  #pragma unroll
  for (int nt=0;nt<8;++nt)
    #pragma unroll
    for (int ks=0;ks<4;++ks){
      bf16x8 wfr = *(const bf16x8*)(W1eq + (nt*16+(l&15))*FF + ks*32 + kg);
      acc[nt] = __builtin_amdgcn_mfma_f32_16x16x32_bf16(wfr, xfrag[ks], acc[nt], 0,0,0);
    }
  #pragma unroll
  for (int nt=0;nt<8;++nt){
    int o0 = nt*16 + r0;
    float4 bb = *(const float4*)(b1eq + o0);
    uint2 u;
    u.x = pk2(silu_f(acc[nt][0]+bb.x), silu_f(acc[nt][1]+bb.y));
    u.y = pk2(silu_f(acc[nt][2]+bb.z), silu_f(acc[nt][3]+bb.w));
    *(uint2*)(&Hs1[le*136 + o0]) = u;
  }
  // ---------------- GEMM1 eme (swapped, no bias) -> Hs2 ----------------
  #pragma unroll
  for (int nt=0;nt<8;++nt) acc[nt] = f32x4{0.f,0.f,0.f,0.f};
  #pragma unroll
  for (int nt=0;nt<8;++nt)
    #pragma unroll
    for (int ks=0;ks<4;++ks){
      bf16x8 wfr = *(const bf16x8*)(W1me + (nt*16+(l&15))*FF + ks*32 + kg);
      acc[nt] = __builtin_amdgcn_mfma_f32_16x16x32_bf16(wfr, xfrag[ks], acc[nt], 0,0,0);
    }
  #pragma unroll
  for (int nt=0;nt<8;++nt){
    int o0 = nt*16 + r0;
    uint2 u;
    u.x = pk2(silu_f(acc[nt][0]), silu_f(acc[nt][1]));
    u.y = pk2(silu_f(acc[nt][2]), silu_f(acc[nt][3]));
    *(uint2*)(&Hs2[le*136 + o0]) = u;
  }
  __syncthreads();

  // ---------------- GEMM2 eqf (unswapped) + masked scal reduce -> afl1 ----------------
  {
    bf16x8 hfr[4];
    #pragma unroll
    for (int ks=0;ks<4;++ks)
      hfr[ks] = *(const bf16x8*)(Hs1 + le*136 + ks*32 + kg);
    #pragma unroll
    for (int nt=0;nt<8;++nt) acc[nt] = f32x4{0.f,0.f,0.f,0.f};
    #pragma unroll
    for (int nt=0;nt<8;++nt)
      #pragma unroll
      for (int ks=0;ks<4;++ks){
        bf16x8 wfr = *(const bf16x8*)(W2eq + (nt*16+(l&15))*FF + ks*32 + kg);
        acc[nt] = __builtin_amdgcn_mfma_f32_16x16x32_bf16(hfr[ks], wfr, acc[nt], 0,0,0);
      }
    #pragma unroll
    for (int nt=0;nt<8;++nt){
      int col = nt*16 + (l&15);
      float bb = b2eq[col];
      float q0=0.f,q1=0.f,q2=0.f;
      #pragma unroll
      for (int r=0;r<4;++r){
        int row = w*16 + r0 + r;
        float ym = (acc[nt][r] + bb) * scal[row][3];
        q0 = fmaf(ym, scal[row][0], q0);
        q1 = fmaf(ym, scal[row][1], q1);
        q2 = fmaf(ym, scal[row][2], q2);
      }
      q0 += __shfl_xor(q0,16); q0 += __shfl_xor(q0,32);
      q1 += __shfl_xor(q1,16); q1 += __shfl_xor(q1,32);
      q2 += __shfl_xor(q2,16); q2 += __shfl_xor(q2,32);
      if (l < 16){
        afl1[w][0*128+col] = q0; afl1[w][1*128+col] = q1; afl1[w][2*128+col] = q2;
      }
    }
  }
  // ---------------- GEMM2 eme (unswapped) + eqdrT float4 gather -> afl2 ----------------
  {
    bf16x8 hfr[4];
    #pragma unroll
    for (int ks=0;ks<4;++ks)
      hfr[ks] = *(const bf16x8*)(Hs2 + le*136 + ks*32 + kg);
    #pragma unroll
    for (int nt=0;nt<8;++nt) acc[nt] = f32x4{0.f,0.f,0.f,0.f};
    #pragma unroll
    for (int nt=0;nt<8;++nt)
      #pragma unroll
      for (int ks=0;ks<4;++ks){
        bf16x8 wfr = *(const bf16x8*)(W2me + (nt*16+(l&15))*FF + ks*32 + kg);
        acc[nt] = __builtin_amdgcn_mfma_f32_16x16x32_bf16(hfr[ks], wfr, acc[nt], 0,0,0);
      }
    #pragma unroll
    for (int nt=0;nt<8;++nt){
      int col = nt*16 + (l&15);
      float q0=0.f,q1=0.f,q2=0.f;
      #pragma unroll
      for (int r=0;r<4;++r){
        int row = w*16 + r0 + r;
        float ym = acc[nt][r] * scal[row][3];
        float4 g = *(const float4*)(eqdrT + ((size_t)nbq[row]*FF + col)*4);
        q0 = fmaf(ym, g.x, q0);
        q1 = fmaf(ym, g.y, q1);
        q2 = fmaf(ym, g.z, q2);
      }
      q0 += __shfl_xor(q0,16); q0 += __shfl_xor(q0,32);
      q1 += __shfl_xor(q1,16); q1 += __shfl_xor(q1,32);
      q2 += __shfl_xor(q2,16); q2 += __shfl_xor(q2,32);
      if (l < 16){
        afl2[w][0*128+col] = q0; afl2[w][1*128+col] = q1; afl2[w][2*128+col] = q2;
      }
    }
  }
  __syncthreads();
  for (int i=t; i<384; i+=256){
    float s1 = afl1[0][i]+afl1[1][i]+afl1[2][i]+afl1[3][i];
    size_t o = (size_t)atom*384 + i;
    updf[o] = s1;
    eqf_out[o] += s1;
    upddr[o] = afl2[0][i]+afl2[1][i]+afl2[2][i]+afl2[3][i];
  }
}

// ---------------- finalize: eq_dr update (+ transposed copy) + inv_node update ----------------
__global__ void k_fin(const float* __restrict__ esu, const float* __restrict__ isu,
                      const float* __restrict__ updf, const float* __restrict__ upddr,
                      const float* __restrict__ eqf, float* __restrict__ eqdr,
                      float* __restrict__ eqdrT, float* __restrict__ inv_node){
  int id = blockIdx.x*256+threadIdx.x;
  int atom = id >> 7, o = id & 127;
  float es = esu[id];
  float sum = 0.f;
  size_t b0 = (size_t)atom*3*FF + o;
  float nd[3];
  #pragma unroll
  for (int c=0;c<3;++c){
    size_t k = b0 + (size_t)c*FF;
    float v = eqdr[k] + upddr[k] + es*updf[k];
    eqdr[k] = v;
    nd[c] = v;
    sum = fmaf(eqf[k], v, sum);
  }
  float4 tv; tv.x=nd[0]; tv.y=nd[1]; tv.z=nd[2]; tv.w=0.f;
  *(float4*)(eqdrT + (size_t)id*4) = tv;
  inv_node[id] = fmaf(-isu[id], sum, inv_node[id]);
}

extern "C" void kernel_launch(void* const* d_in, const int* in_sizes, int n_in,
                              void* d_out, int out_size, void* d_ws, size_t ws_size,
                              hipStream_t stream){
  const int*   z     = (const int*)  d_in[0];
  const int*   nbrs  = (const int*)  d_in[2];
  const float* maskp = (const float*)d_in[3];
  const float* dist  = (const float*)d_in[4];
  const float* dvec  = (const float*)d_in[5];
  const float* emb   = (const float*)d_in[6];
  const float* me_W  = (const float*)d_in[7];
  const float* me_b  = (const float*)d_in[8];
  const float* mn_W1 = (const float*)d_in[9];
  const float* mn_b1 = (const float*)d_in[10];
  const float* mn_W2 = (const float*)d_in[11];
  const float* mn_b2 = (const float*)d_in[12];
  const float* eqc_W = (const float*)d_in[13];
  const float* eqf_W1= (const float*)d_in[14];
  const float* eqf_b1= (const float*)d_in[15];
  const float* eqf_W2= (const float*)d_in[16];
  const float* eqf_b2= (const float*)d_in[17];
  const float* esu_W1= (const float*)d_in[18];
  const float* esu_b1= (const float*)d_in[19];
  const float* esu_W2= (const float*)d_in[20];
  const float* esu_b2= (const float*)d_in[21];
  const float* eme_W1= (const float*)d_in[22];
  const float* eme_W2= (const float*)d_in[23];
  const float* isu_W1= (const float*)d_in[24];
  const float* isu_b1= (const float*)d_in[25];
  const float* isu_W2= (const float*)d_in[26];
  const float* isu_b2= (const float*)d_in[27];

  float* out      = (float*)d_out;
  float* inv_node = out;                        // BA*FF   = 131072
  float* eqF      = out + 131072;               // BA*3    = 3072
  float* eqf      = out + 134144;               // BA*3*FF = 393216
  float* eqdr     = out + 527360;               // BA*3*FF = 393216

  // workspace layout (floats)
  float* w        = (float*)d_ws;
  float* cutw     = w;                          //    65,536
  float* unitv    = w + 65536;                  //   196,608
  float* msg_node = w + 262144;                 //   131,072
  float* esu_o    = w + 393216;                 //   131,072
  float* isu_o    = w + 524288;                 //   131,072
  float* updf     = w + 655360;                 //   393,216
  float* upddr    = w + 1048576;                //   393,216
  float* scalg    = w + 1441792;                //   262,144 (EDG*4)
  float* eqdrT    = w + 1703936;                //   524,288 (BA*FF*4)
  unsigned short* rbf_bf  = (unsigned short*)(w + 2228224); // EDG*32 us = 1,048,576 f
  unsigned short* wbf     = (unsigned short*)(w + 3276800); // 208,896 us = 104,448 f
  unsigned short* inv_msg = (unsigned short*)(w + 3381248); // EDG*FF us = 4,194,304 f

  hipMemsetAsync(out + 131072, 0, (size_t)(3072 + 2*393216)*sizeof(float), stream);
  hipMemsetAsync(eqdrT, 0, (size_t)524288*sizeof(float), stream);

  k_cvtw<<<817, 256, 0, stream>>>(eqf_W1, eqf_W2, eme_W1, eme_W2, me_W, wbf);
  k_init<<<BA*FF/256, 256, 0, stream>>>(z, emb, inv_node);
  k_geom<<<EDG/256,   256, 0, stream>>>(dist, dvec, rbf_bf, cutw, unitv);

  for (int l=0; l<NLAY; ++l){
    size_t oW = (size_t)l*FF*FF, oB = (size_t)l*FF;
    const unsigned short* eqfW1b = wbf + 0*49152 + l*16384;
    const unsigned short* eqfW2b = wbf + 1*49152 + l*16384;
    const unsigned short* emeW1b = wbf + 2*49152 + l*16384;
    const unsigned short* emeW2b = wbf + 3*49152 + l*16384;
    const unsigned short* meWb   = wbf + 196608  + l*4096;

    k_mlp_node3<<<dim3(BA/16, 3), 128, 0, stream>>>(inv_node,
        mn_W1+oW,  mn_b1+oB,  mn_W2+oW,  mn_b2+oB,  msg_node,
        esu_W1+oW, esu_b1+oB, esu_W2+oW, esu_b2+oB, esu_o,
        isu_W1+oW, isu_b1+oB, isu_W2+oW, isu_b2+oB, isu_o);
    k_stage<<<BA, 256, 0, stream>>>(rbf_bf, cutw, unitv, maskp, nbrs, msg_node,
        meWb, me_b+oB, eqc_W+oB, inv_msg, scalg, eqF);
    k_edge2<<<BA, 256, 0, stream>>>(inv_msg,
        eqfW1b, eqf_b1+oB, eqfW2b, eqf_b2+oB, emeW1b, emeW2b,
        scalg, maskp, nbrs, eqdrT, eqf, updf, upddr);
    k_fin<<<BA*FF/256, 256, 0, stream>>>(esu_o, isu_o, updf, upddr, eqf, eqdr, eqdrT, inv_node);
  }
}

// Round 6
// 364.464 us; speedup vs baseline: 1.0284x; 1.0284x over previous
//
#include <hip/hip_runtime.h>
#include <cstdint>
#include <cstddef>

#define BB   4
#define AA   256
#define NNB  64
#define FF   128
#define NBAS 20
#define NLAY 3
#define BA   (BB*AA)        // 1024 atoms total
#define EDG  (BA*NNB)       // 65536 edges

typedef __attribute__((ext_vector_type(8))) short bf16x8;
typedef __attribute__((ext_vector_type(4))) float f32x4;

__device__ __forceinline__ float silu_f(float x){ return x / (1.0f + __expf(-x)); }

// round-to-nearest-even f32 -> bf16 bits
__device__ __forceinline__ unsigned short f2bf(float x){
  unsigned int u = __float_as_uint(x);
  u += 0x7FFFu + ((u >> 16) & 1u);
  return (unsigned short)(u >> 16);
}
__device__ __forceinline__ unsigned int pk2(float a, float b){
  return (unsigned int)f2bf(a) | ((unsigned int)f2bf(b) << 16);
}

// ---------------- init: inv_node = emb[atomic_numbers] ----------------
__global__ void k_init(const int* __restrict__ z, const float* __restrict__ emb,
                       float* __restrict__ inv_node){
  int id = blockIdx.x*256 + threadIdx.x;
  int atom = id >> 7, o = id & 127;
  inv_node[id] = emb[z[atom]*FF + o];
}

// ------------- weight conversion: eqf_W1, eqf_W2, eme_W1, eme_W2 (+ padded me_W) ------------
__global__ void k_cvtw(const float* __restrict__ a, const float* __restrict__ b,
                       const float* __restrict__ c, const float* __restrict__ d,
                       const float* __restrict__ me, unsigned short* __restrict__ out){
  int id = blockIdx.x*256 + threadIdx.x;
  if (id < 196608){
    int reg = id / 49152, off = id - reg*49152;
    const float* src = (reg==0)?a:(reg==1)?b:(reg==2)?c:d;
    out[id] = f2bf(src[off]);
  } else if (id < 196608 + 12288){
    int p = id - 196608;
    int l = p >> 12;            // layer
    int rem = p & 4095;
    int row = rem >> 5, k = rem & 31;
    float v = (k < NBAS) ? me[((size_t)l*FF + row)*NBAS + k] : 0.0f;
    out[id] = f2bf(v);
  }
}

// ---------------- f32 two-pass MLP core over 16 rows (node MLPs) ----------------
__device__ __forceinline__ void mlp16(const float (*xs)[FF], float (*hs)[FF], int o,
    const float* __restrict__ W1, const float* __restrict__ b1,
    const float* __restrict__ W2, const float* __restrict__ b2, float acc[16]){
  #pragma unroll
  for (int r=0;r<16;++r) acc[r] = b1[o];
  #pragma unroll
  for (int ic=0;ic<4;++ic){
    float4 wv[8];
    #pragma unroll
    for (int j=0;j<8;++j) wv[j] = *reinterpret_cast<const float4*>(&W1[(size_t)o*FF + ic*32 + j*4]);
    #pragma unroll
    for (int r=0;r<16;++r){
      #pragma unroll
      for (int j=0;j<8;++j){
        float4 xv = *reinterpret_cast<const float4*>(&xs[r][ic*32+j*4]);
        acc[r] = fmaf(xv.x, wv[j].x, acc[r]);
        acc[r] = fmaf(xv.y, wv[j].y, acc[r]);
        acc[r] = fmaf(xv.z, wv[j].z, acc[r]);
        acc[r] = fmaf(xv.w, wv[j].w, acc[r]);
      }
    }
  }
  #pragma unroll
  for (int r=0;r<16;++r) hs[r][o] = silu_f(acc[r]);
  __syncthreads();
  #pragma unroll
  for (int r=0;r<16;++r) acc[r] = b2[o];
  #pragma unroll
  for (int ic=0;ic<4;++ic){
    float4 wv[8];
    #pragma unroll
    for (int j=0;j<8;++j) wv[j] = *reinterpret_cast<const float4*>(&W2[(size_t)o*FF + ic*32 + j*4]);
    #pragma unroll
    for (int r=0;r<16;++r){
      #pragma unroll
      for (int j=0;j<8;++j){
        float4 xv = *reinterpret_cast<const float4*>(&hs[r][ic*32+j*4]);
        acc[r] = fmaf(xv.x, wv[j].x, acc[r]);
        acc[r] = fmaf(xv.y, wv[j].y, acc[r]);
        acc[r] = fmaf(xv.z, wv[j].z, acc[r]);
        acc[r] = fmaf(xv.w, wv[j].w, acc[r]);
      }
    }
  }
}

// ---------------- three node MLPs in one dispatch (blockIdx.y selects) ----------------
__global__ __launch_bounds__(128) void k_mlp_node3(const float* __restrict__ X,
    const float* W1a, const float* b1a, const float* W2a, const float* b2a, float* Ya,
    const float* W1b, const float* b1b, const float* W2b, const float* b2b, float* Yb,
    const float* W1c, const float* b1c, const float* W2c, const float* b2c, float* Yc){
  const float *W1,*b1,*W2,*b2; float* Y;
  if (blockIdx.y==0){ W1=W1a;b1=b1a;W2=W2a;b2=b2a;Y=Ya; }
  else if (blockIdx.y==1){ W1=W1b;b1=b1b;W2=W2b;b2=b2b;Y=Yb; }
  else { W1=W1c;b1=b1c;W2=W2c;b2=b2c;Y=Yc; }
  __shared__ __align__(16) float xs[16][FF];
  __shared__ __align__(16) float hs[16][FF];
  const int o = threadIdx.x;
  const int row0 = blockIdx.x * 16;
  #pragma unroll
  for (int r=0;r<16;++r) xs[r][o] = X[(size_t)(row0+r)*FF + o];
  __syncthreads();
  float acc[16];
  mlp16(xs, hs, o, W1, b1, W2, b2, acc);
  #pragma unroll
  for (int r=0;r<16;++r) Y[(size_t)(row0+r)*FF + o] = acc[r];
}

// =====================================================================
// Stage kernel: one block = one atom. Inline rbf/cutoff/unit; me-MLP via
// MFMA (swapped); inv_msg (bf16 -> global via LDS), eqmsgF/mask -> scalg,
// eq_F accumulation.
// =====================================================================
__global__ __launch_bounds__(256) void k_stage(
    const float* __restrict__ dist, const float* __restrict__ dvec,
    const float* __restrict__ maskp, const int* __restrict__ nbrs,
    const float* __restrict__ msg_node,
    const unsigned short* __restrict__ meWb, const float* __restrict__ meb,
    const float* __restrict__ eqcW,
    unsigned short* __restrict__ inv_msg, float* __restrict__ scalg,
    float* __restrict__ eqF){
  __shared__ unsigned short Hs[64*136];
  __shared__ float eqFred[4][3];
  const int t = threadIdx.x, w = t>>6, l = t&63;
  const int atom = blockIdx.x;
  const int bbase = (atom/AA)*AA;
  const int le = w*16 + (l&15);
  const int eg = atom*NNB + le;
  const int kg = (l>>4)<<3;
  const int r0 = (l>>4)<<2;

  // inline geometry
  const float d  = dist[eg];
  const float dinv = 1.0f/(d + 1e-8f);
  const float xx = d*0.2f;
  float x2=xx*xx, x4=x2*x2, x6=x4*x2, x7=x6*xx, x8=x7*xx;
  float ct = 1.0f - 28.0f*x6 + 48.0f*x7 - 21.0f*x8;
  ct = (xx < 1.0f) ? ct : 0.0f;
  const float c5 = 0.6283185307179586f;      // pi/5
  bf16x8 rfr;
  #pragma unroll
  for (int i=0;i<8;++i){
    int k = kg + i;
    float v = (k < NBAS) ? __sinf((float)(k+1)*c5*d)*dinv : 0.0f;
    rfr[i] = (short)f2bf(v);
  }

  f32x4 acc[8];
  #pragma unroll
  for (int nt=0;nt<8;++nt){
    bf16x8 wfr = *(const bf16x8*)(meWb + (nt*16 + (l&15))*32 + kg);
    acc[nt] = __builtin_amdgcn_mfma_f32_16x16x32_bf16(wfr, rfr, f32x4{0.f,0.f,0.f,0.f}, 0,0,0);
  }
  const int nbv = bbase + nbrs[eg];
  float pv = 0.f;
  #pragma unroll
  for (int nt=0;nt<8;++nt){
    int o0 = nt*16 + r0;
    float4 mb = *(const float4*)(meb + o0);
    float4 mi = *(const float4*)(msg_node + (size_t)atom*FF + o0);
    float4 mf = *(const float4*)(msg_node + (size_t)nbv*FF + o0);
    float4 ec = *(const float4*)(eqcW + o0);
    float v0 = (acc[nt][0]+mb.x)*ct*mi.x*mf.x;
    float v1 = (acc[nt][1]+mb.y)*ct*mi.y*mf.y;
    float v2 = (acc[nt][2]+mb.z)*ct*mi.z*mf.z;
    float v3 = (acc[nt][3]+mb.w)*ct*mi.w*mf.w;
    pv = fmaf(v0,ec.x, fmaf(v1,ec.y, fmaf(v2,ec.z, fmaf(v3,ec.w, pv))));
    uint2 u; u.x = pk2(v0,v1); u.y = pk2(v2,v3);
    *(uint2*)(&Hs[le*136 + o0]) = u;
  }
  pv += __shfl_xor(pv,16); pv += __shfl_xor(pv,32);
  float cf0=0.f, cf1=0.f, cf2=0.f;
  if (l < 16){
    float m  = maskp[eg];
    float s0 = pv*dvec[(size_t)eg*3+0]*dinv;
    float s1 = pv*dvec[(size_t)eg*3+1]*dinv;
    float s2 = pv*dvec[(size_t)eg*3+2]*dinv;
    float4 sv; sv.x=s0; sv.y=s1; sv.z=s2; sv.w=m;
    *(float4*)(scalg + (size_t)eg*4) = sv;
    cf0 = s0*m; cf1 = s1*m; cf2 = s2*m;
  }
  #pragma unroll
  for (int s2=1; s2<16; s2<<=1){
    cf0 += __shfl_xor(cf0,s2); cf1 += __shfl_xor(cf1,s2); cf2 += __shfl_xor(cf2,s2);
  }
  if (l == 0){ eqFred[w][0]=cf0; eqFred[w][1]=cf1; eqFred[w][2]=cf2; }
  __syncthreads();
  unsigned short* og = inv_msg + (size_t)atom*NNB*FF;
  #pragma unroll
  for (int c=t; c<1024; c+=256){
    int row = c >> 4, ko = (c & 15) << 3;
    *(int4*)(og + row*FF + ko) = *(const int4*)(&Hs[row*136 + ko]);
  }
  if (t < 3) eqF[atom*3+t] += eqFred[0][t]+eqFred[1][t]+eqFred[2][t]+eqFred[3][t];
}

// =====================================================================
// GEMM1 pass: H = silu(X*W1^T (+b1)). W1 staged in LDS, each wave does
// 32 rows (2 m-subtiles), weight fragments reused across subtiles.
// Grid: EDG/128 = 512 blocks, 256 threads.
// =====================================================================
__global__ __launch_bounds__(256) void k_h(
    const unsigned short* __restrict__ X,
    const unsigned short* __restrict__ W1, const float* __restrict__ b1,
    unsigned short* __restrict__ H){
  __shared__ unsigned short Wl[128*136];
  const int t = threadIdx.x, w = t>>6, l = t&63;
  #pragma unroll
  for (int c=t; c<2048; c+=256){
    int row = c >> 4, ko = (c & 15) << 3;
    *(int4*)(&Wl[row*136 + ko]) = *(const int4*)(W1 + row*FF + ko);
  }
  const int kg = (l>>4)<<3;
  const int r0 = (l>>4)<<2;
  const int rowbase = blockIdx.x*128 + w*32;
  bf16x8 xfrag[2][4];
  #pragma unroll
  for (int ms=0;ms<2;++ms)
    #pragma unroll
    for (int ks=0;ks<4;++ks)
      xfrag[ms][ks] = *(const bf16x8*)(X + (size_t)(rowbase + ms*16 + (l&15))*FF + ks*32 + kg);
  __syncthreads();
  f32x4 acc[2][8];
  #pragma unroll
  for (int ms=0;ms<2;++ms)
    #pragma unroll
    for (int nt=0;nt<8;++nt) acc[ms][nt] = f32x4{0.f,0.f,0.f,0.f};
  #pragma unroll
  for (int nt=0;nt<8;++nt)
    #pragma unroll
    for (int ks=0;ks<4;++ks){
      bf16x8 wfr = *(const bf16x8*)(&Wl[(nt*16+(l&15))*136 + ks*32 + kg]);
      #pragma unroll
      for (int ms=0;ms<2;++ms)
        acc[ms][nt] = __builtin_amdgcn_mfma_f32_16x16x32_bf16(wfr, xfrag[ms][ks], acc[ms][nt], 0,0,0);
    }
  #pragma unroll
  for (int ms=0;ms<2;++ms)
    #pragma unroll
    for (int nt=0;nt<8;++nt){
      int o0 = nt*16 + r0;
      float4 bb = b1 ? *(const float4*)(b1 + o0) : float4{0.f,0.f,0.f,0.f};
      uint2 u;
      u.x = pk2(silu_f(acc[ms][nt][0]+bb.x), silu_f(acc[ms][nt][1]+bb.y));
      u.y = pk2(silu_f(acc[ms][nt][2]+bb.z), silu_f(acc[ms][nt][3]+bb.w));
      *(uint2*)(H + (size_t)(rowbase + ms*16 + (l&15))*FF + o0) = u;
    }
}

// =====================================================================
// k_z1: eqf GEMM2 (Z = H*W2^T + b2) + masked eqmsgF row-reduction.
// One block = one atom; H fragments from global; LDS ~7 KB.
// =====================================================================
__global__ __launch_bounds__(256) void k_z1(
    const unsigned short* __restrict__ H,
    const unsigned short* __restrict__ W2, const float* __restrict__ b2,
    const float* __restrict__ scalg,
    float* __restrict__ eqf_out, float* __restrict__ updf){
  __shared__ float scal[64][4];
  __shared__ float afl[4][384];
  const int t = threadIdx.x, w = t>>6, l = t&63;
  const int atom = blockIdx.x;
  const int le = w*16 + (l&15);
  const int kg = (l>>4)<<3;
  const int r0 = (l>>4)<<2;
  if (t < 64){
    float4 s = *(const float4*)(scalg + (size_t)(atom*NNB + t)*4);
    scal[t][0]=s.x; scal[t][1]=s.y; scal[t][2]=s.z; scal[t][3]=s.w;
  }
  bf16x8 hfr[4];
  #pragma unroll
  for (int ks=0;ks<4;++ks)
    hfr[ks] = *(const bf16x8*)(H + ((size_t)atom*NNB + le)*FF + ks*32 + kg);
  __syncthreads();
  f32x4 acc[8];
  #pragma unroll
  for (int nt=0;nt<8;++nt) acc[nt] = f32x4{0.f,0.f,0.f,0.f};
  #pragma unroll
  for (int nt=0;nt<8;++nt)
    #pragma unroll
    for (int ks=0;ks<4;++ks){
      bf16x8 wfr = *(const bf16x8*)(W2 + (nt*16+(l&15))*FF + ks*32 + kg);
      acc[nt] = __builtin_amdgcn_mfma_f32_16x16x32_bf16(hfr[ks], wfr, acc[nt], 0,0,0);
    }
  #pragma unroll
  for (int nt=0;nt<8;++nt){
    int col = nt*16 + (l&15);
    float bb = b2[col];
    float q0=0.f,q1=0.f,q2=0.f;
    #pragma unroll
    for (int r=0;r<4;++r){
      int row = w*16 + r0 + r;
      float ym = (acc[nt][r] + bb) * scal[row][3];
      q0 = fmaf(ym, scal[row][0], q0);
      q1 = fmaf(ym, scal[row][1], q1);
      q2 = fmaf(ym, scal[row][2], q2);
    }
    q0 += __shfl_xor(q0,16); q0 += __shfl_xor(q0,32);
    q1 += __shfl_xor(q1,16); q1 += __shfl_xor(q1,32);
    q2 += __shfl_xor(q2,16); q2 += __shfl_xor(q2,32);
    if (l < 16){
      afl[w][0*128+col] = q0; afl[w][1*128+col] = q1; afl[w][2*128+col] = q2;
    }
  }
  __syncthreads();
  for (int i=t; i<384; i+=256){
    float s = afl[0][i]+afl[1][i]+afl[2][i]+afl[3][i];
    size_t o = (size_t)atom*384 + i;
    updf[o] = s;
    eqf_out[o] += s;
  }
}

// =====================================================================
// k_z2: eme GEMM2 (no bias) + eq_dr neighbor-gather reduction (eqdrT float4).
// =====================================================================
__global__ __launch_bounds__(256) void k_z2(
    const unsigned short* __restrict__ H,
    const unsigned short* __restrict__ W2,
    const float* __restrict__ maskp, const int* __restrict__ nbrs,
    const float* __restrict__ eqdrT,
    float* __restrict__ upddr){
  __shared__ float maskL[64];
  __shared__ int   nbq[64];
  __shared__ float afl[4][384];
  const int t = threadIdx.x, w = t>>6, l = t&63;
  const int atom = blockIdx.x;
  const int le = w*16 + (l&15);
  const int kg = (l>>4)<<3;
  const int r0 = (l>>4)<<2;
  if (t < 64){
    int e2 = atom*NNB + t;
    maskL[t] = maskp[e2];
    nbq[t]   = (atom/AA)*AA + nbrs[e2];
  }
  bf16x8 hfr[4];
  #pragma unroll
  for (int ks=0;ks<4;++ks)
    hfr[ks] = *(const bf16x8*)(H + ((size_t)atom*NNB + le)*FF + ks*32 + kg);
  __syncthreads();
  f32x4 acc[8];
  #pragma unroll
  for (int nt=0;nt<8;++nt) acc[nt] = f32x4{0.f,0.f,0.f,0.f};
  #pragma unroll
  for (int nt=0;nt<8;++nt)
    #pragma unroll
    for (int ks=0;ks<4;++ks){
      bf16x8 wfr = *(const bf16x8*)(W2 + (nt*16+(l&15))*FF + ks*32 + kg);
      acc[nt] = __builtin_amdgcn_mfma_f32_16x16x32_bf16(hfr[ks], wfr, acc[nt], 0,0,0);
    }
  #pragma unroll
  for (int nt=0;nt<8;++nt){
    int col = nt*16 + (l&15);
    float q0=0.f,q1=0.f,q2=0.f;
    #pragma unroll
    for (int r=0;r<4;++r){
      int row = w*16 + r0 + r;
      float ym = acc[nt][r] * maskL[row];
      float4 g = *(const float4*)(eqdrT + ((size_t)nbq[row]*FF + col)*4);
      q0 = fmaf(ym, g.x, q0);
      q1 = fmaf(ym, g.y, q1);
      q2 = fmaf(ym, g.z, q2);
    }
    q0 += __shfl_xor(q0,16); q0 += __shfl_xor(q0,32);
    q1 += __shfl_xor(q1,16); q1 += __shfl_xor(q1,32);
    q2 += __shfl_xor(q2,16); q2 += __shfl_xor(q2,32);
    if (l < 16){
      afl[w][0*128+col] = q0; afl[w][1*128+col] = q1; afl[w][2*128+col] = q2;
    }
  }
  __syncthreads();
  for (int i=t; i<384; i+=256){
    upddr[(size_t)atom*384 + i] = afl[0][i]+afl[1][i]+afl[2][i]+afl[3][i];
  }
}

// ---------------- finalize: eq_dr update (+ transposed copy) + inv_node update ----------------
__global__ void k_fin(const float* __restrict__ esu, const float* __restrict__ isu,
                      const float* __restrict__ updf, const float* __restrict__ upddr,
                      const float* __restrict__ eqf, float* __restrict__ eqdr,
                      float* __restrict__ eqdrT, float* __restrict__ inv_node){
  int id = blockIdx.x*256+threadIdx.x;
  int atom = id >> 7, o = id & 127;
  float es = esu[id];
  float sum = 0.f;
  size_t b0 = (size_t)atom*3*FF + o;
  float nd[3];
  #pragma unroll
  for (int c=0;c<3;++c){
    size_t k = b0 + (size_t)c*FF;
    float v = eqdr[k] + upddr[k] + es*updf[k];
    eqdr[k] = v;
    nd[c] = v;
    sum = fmaf(eqf[k], v, sum);
  }
  float4 tv; tv.x=nd[0]; tv.y=nd[1]; tv.z=nd[2]; tv.w=0.f;
  *(float4*)(eqdrT + (size_t)id*4) = tv;
  inv_node[id] = fmaf(-isu[id], sum, inv_node[id]);
}

extern "C" void kernel_launch(void* const* d_in, const int* in_sizes, int n_in,
                              void* d_out, int out_size, void* d_ws, size_t ws_size,
                              hipStream_t stream){
  const int*   z     = (const int*)  d_in[0];
  const int*   nbrs  = (const int*)  d_in[2];
  const float* maskp = (const float*)d_in[3];
  const float* dist  = (const float*)d_in[4];
  const float* dvec  = (const float*)d_in[5];
  const float* emb   = (const float*)d_in[6];
  const float* me_W  = (const float*)d_in[7];
  const float* me_b  = (const float*)d_in[8];
  const float* mn_W1 = (const float*)d_in[9];
  const float* mn_b1 = (const float*)d_in[10];
  const float* mn_W2 = (const float*)d_in[11];
  const float* mn_b2 = (const float*)d_in[12];
  const float* eqc_W = (const float*)d_in[13];
  const float* eqf_W1= (const float*)d_in[14];
  const float* eqf_b1= (const float*)d_in[15];
  const float* eqf_W2= (const float*)d_in[16];
  const float* eqf_b2= (const float*)d_in[17];
  const float* esu_W1= (const float*)d_in[18];
  const float* esu_b1= (const float*)d_in[19];
  const float* esu_W2= (const float*)d_in[20];
  const float* esu_b2= (const float*)d_in[21];
  const float* eme_W1= (const float*)d_in[22];
  const float* eme_W2= (const float*)d_in[23];
  const float* isu_W1= (const float*)d_in[24];
  const float* isu_b1= (const float*)d_in[25];
  const float* isu_W2= (const float*)d_in[26];
  const float* isu_b2= (const float*)d_in[27];

  float* out      = (float*)d_out;
  float* inv_node = out;                        // BA*FF   = 131072
  float* eqF      = out + 131072;               // BA*3    = 3072
  float* eqf      = out + 134144;               // BA*3*FF = 393216
  float* eqdr     = out + 527360;               // BA*3*FF = 393216

  // workspace layout (floats), total 10,459,136 floats = 41.8 MB
  float* w        = (float*)d_ws;
  float* msg_node = w;                          //   131,072
  float* esu_o    = w + 131072;                 //   131,072
  float* isu_o    = w + 262144;                 //   131,072
  float* updf     = w + 393216;                 //   393,216
  float* upddr    = w + 786432;                 //   393,216
  float* scalg    = w + 1179648;                //   262,144 (EDG*4)
  float* eqdrT    = w + 1441792;                //   524,288 (BA*FF*4)
  unsigned short* wbf     = (unsigned short*)(w + 1966080); // 208,896 us = 104,448 f
  unsigned short* inv_msg = (unsigned short*)(w + 2070528); // EDG*FF us = 4,194,304 f
  unsigned short* Hbuf    = (unsigned short*)(w + 6264832); // EDG*FF us = 4,194,304 f

  hipMemsetAsync(out + 131072, 0, (size_t)(3072 + 2*393216)*sizeof(float), stream);
  hipMemsetAsync(eqdrT, 0, (size_t)524288*sizeof(float), stream);

  k_cvtw<<<817, 256, 0, stream>>>(eqf_W1, eqf_W2, eme_W1, eme_W2, me_W, wbf);
  k_init<<<BA*FF/256, 256, 0, stream>>>(z, emb, inv_node);

  for (int l=0; l<NLAY; ++l){
    size_t oW = (size_t)l*FF*FF, oB = (size_t)l*FF;
    const unsigned short* eqfW1b = wbf + 0*49152 + l*16384;
    const unsigned short* eqfW2b = wbf + 1*49152 + l*16384;
    const unsigned short* emeW1b = wbf + 2*49152 + l*16384;
    const unsigned short* emeW2b = wbf + 3*49152 + l*16384;
    const unsigned short* meWb   = wbf + 196608  + l*4096;

    k_mlp_node3<<<dim3(BA/16, 3), 128, 0, stream>>>(inv_node,
        mn_W1+oW,  mn_b1+oB,  mn_W2+oW,  mn_b2+oB,  msg_node,
        esu_W1+oW, esu_b1+oB, esu_W2+oW, esu_b2+oB, esu_o,
        isu_W1+oW, isu_b1+oB, isu_W2+oW, isu_b2+oB, isu_o);
    k_stage<<<BA, 256, 0, stream>>>(dist, dvec, maskp, nbrs, msg_node,
        meWb, me_b+oB, eqc_W+oB, inv_msg, scalg, eqF);
    // eqf path
    k_h<<<EDG/128, 256, 0, stream>>>(inv_msg, eqfW1b, eqf_b1+oB, Hbuf);
    k_z1<<<BA, 256, 0, stream>>>(Hbuf, eqfW2b, eqf_b2+oB, scalg, eqf, updf);
    // eme path
    k_h<<<EDG/128, 256, 0, stream>>>(inv_msg, emeW1b, nullptr, Hbuf);
    k_z2<<<BA, 256, 0, stream>>>(Hbuf, emeW2b, maskp, nbrs, eqdrT, upddr);
    k_fin<<<BA*FF/256, 256, 0, stream>>>(esu_o, isu_o, updf, upddr, eqf, eqdr, eqdrT, inv_node);
  }
}

// Round 7
// 258.739 us; speedup vs baseline: 1.4487x; 1.4086x over previous
//
#include <hip/hip_runtime.h>
#include <cstdint>
#include <cstddef>

#define BB   4
#define AA   256
#define NNB  64
#define FF   128
#define NBAS 20
#define NLAY 3
#define BA   (BB*AA)        // 1024 atoms total
#define EDG  (BA*NNB)       // 65536 edges

typedef __attribute__((ext_vector_type(8))) short bf16x8;
typedef __attribute__((ext_vector_type(4))) float f32x4;

__device__ __forceinline__ float silu_f(float x){ return x / (1.0f + __expf(-x)); }

// round-to-nearest-even f32 -> bf16 bits
__device__ __forceinline__ unsigned short f2bf(float x){
  unsigned int u = __float_as_uint(x);
  u += 0x7FFFu + ((u >> 16) & 1u);
  return (unsigned short)(u >> 16);
}
__device__ __forceinline__ unsigned int pk2(float a, float b){
  return (unsigned int)f2bf(a) | ((unsigned int)f2bf(b) << 16);
}

// ---------------- init: inv_node = emb[atomic_numbers] ----------------
__global__ void k_init(const int* __restrict__ z, const float* __restrict__ emb,
                       float* __restrict__ inv_node){
  int id = blockIdx.x*256 + threadIdx.x;
  int atom = id >> 7, o = id & 127;
  inv_node[id] = emb[z[atom]*FF + o];
}

// ------------- weight conversion: eqf_W1, eqf_W2, eme_W1, eme_W2 (+ padded me_W) ------------
__global__ void k_cvtw(const float* __restrict__ a, const float* __restrict__ b,
                       const float* __restrict__ c, const float* __restrict__ d,
                       const float* __restrict__ me, unsigned short* __restrict__ out){
  int id = blockIdx.x*256 + threadIdx.x;
  if (id < 196608){
    int reg = id / 49152, off = id - reg*49152;
    const float* src = (reg==0)?a:(reg==1)?b:(reg==2)?c:d;
    out[id] = f2bf(src[off]);
  } else if (id < 196608 + 12288){
    int p = id - 196608;
    int l = p >> 12;            // layer
    int rem = p & 4095;
    int row = rem >> 5, k = rem & 31;
    float v = (k < NBAS) ? me[((size_t)l*FF + row)*NBAS + k] : 0.0f;
    out[id] = f2bf(v);
  }
}

// ---------------- f32 two-pass MLP core over 16 rows (node MLPs) ----------------
__device__ __forceinline__ void mlp16(const float (*xs)[FF], float (*hs)[FF], int o,
    const float* __restrict__ W1, const float* __restrict__ b1,
    const float* __restrict__ W2, const float* __restrict__ b2, float acc[16]){
  #pragma unroll
  for (int r=0;r<16;++r) acc[r] = b1[o];
  #pragma unroll
  for (int ic=0;ic<4;++ic){
    float4 wv[8];
    #pragma unroll
    for (int j=0;j<8;++j) wv[j] = *reinterpret_cast<const float4*>(&W1[(size_t)o*FF + ic*32 + j*4]);
    #pragma unroll
    for (int r=0;r<16;++r){
      #pragma unroll
      for (int j=0;j<8;++j){
        float4 xv = *reinterpret_cast<const float4*>(&xs[r][ic*32+j*4]);
        acc[r] = fmaf(xv.x, wv[j].x, acc[r]);
        acc[r] = fmaf(xv.y, wv[j].y, acc[r]);
        acc[r] = fmaf(xv.z, wv[j].z, acc[r]);
        acc[r] = fmaf(xv.w, wv[j].w, acc[r]);
      }
    }
  }
  #pragma unroll
  for (int r=0;r<16;++r) hs[r][o] = silu_f(acc[r]);
  __syncthreads();
  #pragma unroll
  for (int r=0;r<16;++r) acc[r] = b2[o];
  #pragma unroll
  for (int ic=0;ic<4;++ic){
    float4 wv[8];
    #pragma unroll
    for (int j=0;j<8;++j) wv[j] = *reinterpret_cast<const float4*>(&W2[(size_t)o*FF + ic*32 + j*4]);
    #pragma unroll
    for (int r=0;r<16;++r){
      #pragma unroll
      for (int j=0;j<8;++j){
        float4 xv = *reinterpret_cast<const float4*>(&hs[r][ic*32+j*4]);
        acc[r] = fmaf(xv.x, wv[j].x, acc[r]);
        acc[r] = fmaf(xv.y, wv[j].y, acc[r]);
        acc[r] = fmaf(xv.z, wv[j].z, acc[r]);
        acc[r] = fmaf(xv.w, wv[j].w, acc[r]);
      }
    }
  }
}

// ---------------- three node MLPs in one dispatch (blockIdx.y selects) ----------------
__global__ __launch_bounds__(128) void k_mlp_node3(const float* __restrict__ X,
    const float* W1a, const float* b1a, const float* W2a, const float* b2a, float* Ya,
    const float* W1b, const float* b1b, const float* W2b, const float* b2b, float* Yb,
    const float* W1c, const float* b1c, const float* W2c, const float* b2c, float* Yc){
  const float *W1,*b1,*W2,*b2; float* Y;
  if (blockIdx.y==0){ W1=W1a;b1=b1a;W2=W2a;b2=b2a;Y=Ya; }
  else if (blockIdx.y==1){ W1=W1b;b1=b1b;W2=W2b;b2=b2b;Y=Yb; }
  else { W1=W1c;b1=b1c;W2=W2c;b2=b2c;Y=Yc; }
  __shared__ __align__(16) float xs[16][FF];
  __shared__ __align__(16) float hs[16][FF];
  const int o = threadIdx.x;
  const int row0 = blockIdx.x * 16;
  #pragma unroll
  for (int r=0;r<16;++r) xs[r][o] = X[(size_t)(row0+r)*FF + o];
  __syncthreads();
  float acc[16];
  mlp16(xs, hs, o, W1, b1, W2, b2, acc);
  #pragma unroll
  for (int r=0;r<16;++r) Y[(size_t)(row0+r)*FF + o] = acc[r];
}

// =====================================================================
// k_edge1: grid 512, 2 atoms (128 edges) per block.
//   phase A (stage, per atom p=0,1): inline geometry, me-MLP via MFMA
//     (swapped), inv_msg -> LDS Xs (packed bf16), scalg + eqF.
//   phase B: X fragments -> registers; LDS reused to stage W1eq then
//     W1me; GEMM1s (swapped) -> H1, H2 (bf16 global).
// =====================================================================
__global__ __launch_bounds__(256) void k_edge1(
    const float* __restrict__ dist, const float* __restrict__ dvec,
    const float* __restrict__ maskp, const int* __restrict__ nbrs,
    const float* __restrict__ msg_node,
    const unsigned short* __restrict__ meWb, const float* __restrict__ meb,
    const float* __restrict__ eqcW,
    const unsigned short* __restrict__ W1eq, const float* __restrict__ b1eq,
    const unsigned short* __restrict__ W1me,
    unsigned short* __restrict__ H1, unsigned short* __restrict__ H2,
    float* __restrict__ scalg, float* __restrict__ eqF){
  __shared__ unsigned short Xs[128*136];
  __shared__ float eqFred[4][2][3];
  const int t = threadIdx.x, w = t>>6, l = t&63;
  const int bid = blockIdx.x, a0 = bid*2;
  const int g = l&15, kg = (l>>4)<<3, r0 = (l>>4)<<2;
  const float c5 = 0.6283185307179586f;      // pi/5

  #pragma unroll
  for (int p=0;p<2;++p){
    const int atom = a0 + p;
    const int eg = atom*NNB + w*16 + g;
    const float d = dist[eg];
    const float dinv = 1.0f/(d + 1e-8f);
    const float xx = d*0.2f;
    float x2=xx*xx, x4=x2*x2, x6=x4*x2, x7=x6*xx, x8=x7*xx;
    float ct = 1.0f - 28.0f*x6 + 48.0f*x7 - 21.0f*x8;
    ct = (xx < 1.0f) ? ct : 0.0f;
    bf16x8 rfr;
    #pragma unroll
    for (int i=0;i<8;++i){
      int k = kg + i;
      float v = (k < NBAS) ? __sinf((float)(k+1)*c5*d)*dinv : 0.0f;
      rfr[i] = (short)f2bf(v);
    }
    f32x4 acc[8];
    #pragma unroll
    for (int nt=0;nt<8;++nt){
      bf16x8 wfr = *(const bf16x8*)(meWb + (nt*16 + g)*32 + kg);
      acc[nt] = __builtin_amdgcn_mfma_f32_16x16x32_bf16(wfr, rfr, f32x4{0.f,0.f,0.f,0.f}, 0,0,0);
    }
    const int bbase = (atom/AA)*AA;
    const int nbv = bbase + nbrs[eg];
    float pv = 0.f;
    #pragma unroll
    for (int nt=0;nt<8;++nt){
      int o0 = nt*16 + r0;
      float4 mb = *(const float4*)(meb + o0);
      float4 mi = *(const float4*)(msg_node + (size_t)atom*FF + o0);
      float4 mf = *(const float4*)(msg_node + (size_t)nbv*FF + o0);
      float4 ec = *(const float4*)(eqcW + o0);
      float v0 = (acc[nt][0]+mb.x)*ct*mi.x*mf.x;
      float v1 = (acc[nt][1]+mb.y)*ct*mi.y*mf.y;
      float v2 = (acc[nt][2]+mb.z)*ct*mi.z*mf.z;
      float v3 = (acc[nt][3]+mb.w)*ct*mi.w*mf.w;
      pv = fmaf(v0,ec.x, fmaf(v1,ec.y, fmaf(v2,ec.z, fmaf(v3,ec.w, pv))));
      uint2 u; u.x = pk2(v0,v1); u.y = pk2(v2,v3);
      *(uint2*)(&Xs[(p*64 + w*16 + g)*136 + o0]) = u;
    }
    pv += __shfl_xor(pv,16); pv += __shfl_xor(pv,32);
    float cf0=0.f, cf1=0.f, cf2=0.f;
    if (l < 16){
      float m  = maskp[eg];
      float s0 = pv*dvec[(size_t)eg*3+0]*dinv;
      float s1 = pv*dvec[(size_t)eg*3+1]*dinv;
      float s2 = pv*dvec[(size_t)eg*3+2]*dinv;
      float4 sv; sv.x=s0; sv.y=s1; sv.z=s2; sv.w=m;
      *(float4*)(scalg + (size_t)eg*4) = sv;
      cf0 = s0*m; cf1 = s1*m; cf2 = s2*m;
    }
    #pragma unroll
    for (int s2=1; s2<16; s2<<=1){
      cf0 += __shfl_xor(cf0,s2); cf1 += __shfl_xor(cf1,s2); cf2 += __shfl_xor(cf2,s2);
    }
    if (l == 0){ eqFred[w][p][0]=cf0; eqFred[w][p][1]=cf1; eqFred[w][p][2]=cf2; }
  }
  __syncthreads();

  // X fragments -> registers (rows w*32 .. w*32+31); eq_F final write
  bf16x8 xf[2][4];
  #pragma unroll
  for (int ms=0;ms<2;++ms)
    #pragma unroll
    for (int ks=0;ks<4;++ks)
      xf[ms][ks] = *(const bf16x8*)(&Xs[(w*32 + ms*16 + g)*136 + ks*32 + kg]);
  if (t < 6){
    int p = t/3, c = t - p*3;
    eqF[(a0+p)*3 + c] += eqFred[0][p][c]+eqFred[1][p][c]+eqFred[2][p][c]+eqFred[3][p][c];
  }
  __syncthreads();

  // ---- stage W1eq into Xs; GEMM1-eqf -> H1 ----
  #pragma unroll
  for (int c=t; c<2048; c+=256){
    int row = c >> 4, ko = (c & 15) << 3;
    *(int4*)(&Xs[row*136 + ko]) = *(const int4*)(W1eq + row*FF + ko);
  }
  __syncthreads();
  f32x4 acc2[2][8];
  #pragma unroll
  for (int ms=0;ms<2;++ms)
    #pragma unroll
    for (int nt=0;nt<8;++nt) acc2[ms][nt] = f32x4{0.f,0.f,0.f,0.f};
  #pragma unroll
  for (int nt=0;nt<8;++nt)
    #pragma unroll
    for (int ks=0;ks<4;++ks){
      bf16x8 wfr = *(const bf16x8*)(&Xs[(nt*16+g)*136 + ks*32 + kg]);
      #pragma unroll
      for (int ms=0;ms<2;++ms)
        acc2[ms][nt] = __builtin_amdgcn_mfma_f32_16x16x32_bf16(wfr, xf[ms][ks], acc2[ms][nt], 0,0,0);
    }
  #pragma unroll
  for (int ms=0;ms<2;++ms)
    #pragma unroll
    for (int nt=0;nt<8;++nt){
      int o0 = nt*16 + r0;
      float4 bb = *(const float4*)(b1eq + o0);
      uint2 u;
      u.x = pk2(silu_f(acc2[ms][nt][0]+bb.x), silu_f(acc2[ms][nt][1]+bb.y));
      u.y = pk2(silu_f(acc2[ms][nt][2]+bb.z), silu_f(acc2[ms][nt][3]+bb.w));
      *(uint2*)(H1 + (size_t)(bid*128 + w*32 + ms*16 + g)*FF + o0) = u;
    }
  __syncthreads();

  // ---- stage W1me into Xs; GEMM1-eme -> H2 ----
  #pragma unroll
  for (int c=t; c<2048; c+=256){
    int row = c >> 4, ko = (c & 15) << 3;
    *(int4*)(&Xs[row*136 + ko]) = *(const int4*)(W1me + row*FF + ko);
  }
  __syncthreads();
  #pragma unroll
  for (int ms=0;ms<2;++ms)
    #pragma unroll
    for (int nt=0;nt<8;++nt) acc2[ms][nt] = f32x4{0.f,0.f,0.f,0.f};
  #pragma unroll
  for (int nt=0;nt<8;++nt)
    #pragma unroll
    for (int ks=0;ks<4;++ks){
      bf16x8 wfr = *(const bf16x8*)(&Xs[(nt*16+g)*136 + ks*32 + kg]);
      #pragma unroll
      for (int ms=0;ms<2;++ms)
        acc2[ms][nt] = __builtin_amdgcn_mfma_f32_16x16x32_bf16(wfr, xf[ms][ks], acc2[ms][nt], 0,0,0);
    }
  #pragma unroll
  for (int ms=0;ms<2;++ms)
    #pragma unroll
    for (int nt=0;nt<8;++nt){
      int o0 = nt*16 + r0;
      uint2 u;
      u.x = pk2(silu_f(acc2[ms][nt][0]), silu_f(acc2[ms][nt][1]));
      u.y = pk2(silu_f(acc2[ms][nt][2]), silu_f(acc2[ms][nt][3]));
      *(uint2*)(H2 + (size_t)(bid*128 + w*32 + ms*16 + g)*FF + o0) = u;
    }
}

// =====================================================================
// k_z: grid 1024 (one atom). Both GEMM2s (W2s LDS-staged) + reductions +
// merged finalize: eqf/eqdr/inv_node updates, eqdrT ping-pong write.
// =====================================================================
__global__ __launch_bounds__(256) void k_z(
    const unsigned short* __restrict__ H1, const unsigned short* __restrict__ H2,
    const unsigned short* __restrict__ W2eq, const float* __restrict__ b2eq,
    const unsigned short* __restrict__ W2me,
    const float* __restrict__ scalg, const int* __restrict__ nbrs,
    const float* __restrict__ eqdrT_prev, float* __restrict__ eqdrT_next,
    const float* __restrict__ esu, const float* __restrict__ isu,
    float* __restrict__ eqf_out, float* __restrict__ eqdr,
    float* __restrict__ inv_node){
  __shared__ unsigned short Wl[128*136];
  __shared__ float scal[64][4];
  __shared__ int   nbq[64];
  __shared__ float afl1[4][384];
  __shared__ float afl2[4][384];
  const int t = threadIdx.x, w = t>>6, l = t&63;
  const int atom = blockIdx.x;
  const int g = l&15, le = w*16 + g;
  const int kg = (l>>4)<<3, r0 = (l>>4)<<2;

  if (t < 64){
    float4 s = *(const float4*)(scalg + (size_t)(atom*NNB + t)*4);
    scal[t][0]=s.x; scal[t][1]=s.y; scal[t][2]=s.z; scal[t][3]=s.w;
    nbq[t] = (atom/AA)*AA + nbrs[atom*NNB + t];
  }
  bf16x8 hfr1[4], hfr2[4];
  #pragma unroll
  for (int ks=0;ks<4;++ks){
    hfr1[ks] = *(const bf16x8*)(H1 + ((size_t)atom*NNB + le)*FF + ks*32 + kg);
    hfr2[ks] = *(const bf16x8*)(H2 + ((size_t)atom*NNB + le)*FF + ks*32 + kg);
  }
  // ---- stage W2eq; GEMM2-eqf + masked scal reduce -> afl1 ----
  #pragma unroll
  for (int c=t; c<2048; c+=256){
    int row = c >> 4, ko = (c & 15) << 3;
    *(int4*)(&Wl[row*136 + ko]) = *(const int4*)(W2eq + row*FF + ko);
  }
  __syncthreads();
  f32x4 acc[8];
  #pragma unroll
  for (int nt=0;nt<8;++nt) acc[nt] = f32x4{0.f,0.f,0.f,0.f};
  #pragma unroll
  for (int nt=0;nt<8;++nt)
    #pragma unroll
    for (int ks=0;ks<4;++ks){
      bf16x8 wfr = *(const bf16x8*)(&Wl[(nt*16+g)*136 + ks*32 + kg]);
      acc[nt] = __builtin_amdgcn_mfma_f32_16x16x32_bf16(hfr1[ks], wfr, acc[nt], 0,0,0);
    }
  #pragma unroll
  for (int nt=0;nt<8;++nt){
    int col = nt*16 + g;
    float bb = b2eq[col];
    float q0=0.f,q1=0.f,q2=0.f;
    #pragma unroll
    for (int r=0;r<4;++r){
      int row = w*16 + r0 + r;
      float ym = (acc[nt][r] + bb) * scal[row][3];
      q0 = fmaf(ym, scal[row][0], q0);
      q1 = fmaf(ym, scal[row][1], q1);
      q2 = fmaf(ym, scal[row][2], q2);
    }
    q0 += __shfl_xor(q0,16); q0 += __shfl_xor(q0,32);
    q1 += __shfl_xor(q1,16); q1 += __shfl_xor(q1,32);
    q2 += __shfl_xor(q2,16); q2 += __shfl_xor(q2,32);
    if (l < 16){
      afl1[w][0*128+col] = q0; afl1[w][1*128+col] = q1; afl1[w][2*128+col] = q2;
    }
  }
  __syncthreads();
  // ---- stage W2me; GEMM2-eme + eqdrT_prev gather reduce -> afl2 ----
  #pragma unroll
  for (int c=t; c<2048; c+=256){
    int row = c >> 4, ko = (c & 15) << 3;
    *(int4*)(&Wl[row*136 + ko]) = *(const int4*)(W2me + row*FF + ko);
  }
  __syncthreads();
  #pragma unroll
  for (int nt=0;nt<8;++nt) acc[nt] = f32x4{0.f,0.f,0.f,0.f};
  #pragma unroll
  for (int nt=0;nt<8;++nt)
    #pragma unroll
    for (int ks=0;ks<4;++ks){
      bf16x8 wfr = *(const bf16x8*)(&Wl[(nt*16+g)*136 + ks*32 + kg]);
      acc[nt] = __builtin_amdgcn_mfma_f32_16x16x32_bf16(hfr2[ks], wfr, acc[nt], 0,0,0);
    }
  #pragma unroll
  for (int nt=0;nt<8;++nt){
    int col = nt*16 + g;
    float q0=0.f,q1=0.f,q2=0.f;
    #pragma unroll
    for (int r=0;r<4;++r){
      int row = w*16 + r0 + r;
      float ym = acc[nt][r] * scal[row][3];
      float4 gv = *(const float4*)(eqdrT_prev + ((size_t)nbq[row]*FF + col)*4);
      q0 = fmaf(ym, gv.x, q0);
      q1 = fmaf(ym, gv.y, q1);
      q2 = fmaf(ym, gv.z, q2);
    }
    q0 += __shfl_xor(q0,16); q0 += __shfl_xor(q0,32);
    q1 += __shfl_xor(q1,16); q1 += __shfl_xor(q1,32);
    q2 += __shfl_xor(q2,16); q2 += __shfl_xor(q2,32);
    if (l < 16){
      afl2[w][0*128+col] = q0; afl2[w][1*128+col] = q1; afl2[w][2*128+col] = q2;
    }
  }
  __syncthreads();
  // ---- merged finalize ----
  for (int i=t; i<384; i+=256){
    int o = i & 127;
    int c = i >> 7;
    float s1 = afl1[0][i]+afl1[1][i]+afl1[2][i]+afl1[3][i];
    float s2 = afl2[0][i]+afl2[1][i]+afl2[2][i]+afl2[3][i];
    size_t idx = (size_t)atom*384 + i;
    float ef = eqf_out[idx] + s1;
    eqf_out[idx] = ef;
    float es = esu[(size_t)atom*FF + o];
    float v = eqdr[idx] + s2 + es*s1;
    eqdr[idx] = v;
    eqdrT_next[((size_t)atom*FF + o)*4 + c] = v;
    afl1[0][i] = ef * v;                       // reuse for cross-c sum
  }
  __syncthreads();
  if (t < 128){
    float sum3 = afl1[0][t] + afl1[0][128+t] + afl1[0][256+t];
    size_t idx = (size_t)atom*FF + t;
    inv_node[idx] = fmaf(-isu[idx], sum3, inv_node[idx]);
  }
}

extern "C" void kernel_launch(void* const* d_in, const int* in_sizes, int n_in,
                              void* d_out, int out_size, void* d_ws, size_t ws_size,
                              hipStream_t stream){
  const int*   z     = (const int*)  d_in[0];
  const int*   nbrs  = (const int*)  d_in[2];
  const float* maskp = (const float*)d_in[3];
  const float* dist  = (const float*)d_in[4];
  const float* dvec  = (const float*)d_in[5];
  const float* emb   = (const float*)d_in[6];
  const float* me_W  = (const float*)d_in[7];
  const float* me_b  = (const float*)d_in[8];
  const float* mn_W1 = (const float*)d_in[9];
  const float* mn_b1 = (const float*)d_in[10];
  const float* mn_W2 = (const float*)d_in[11];
  const float* mn_b2 = (const float*)d_in[12];
  const float* eqc_W = (const float*)d_in[13];
  const float* eqf_W1= (const float*)d_in[14];
  const float* eqf_b1= (const float*)d_in[15];
  const float* eqf_W2= (const float*)d_in[16];
  const float* eqf_b2= (const float*)d_in[17];
  const float* esu_W1= (const float*)d_in[18];
  const float* esu_b1= (const float*)d_in[19];
  const float* esu_W2= (const float*)d_in[20];
  const float* esu_b2= (const float*)d_in[21];
  const float* eme_W1= (const float*)d_in[22];
  const float* eme_W2= (const float*)d_in[23];
  const float* isu_W1= (const float*)d_in[24];
  const float* isu_b1= (const float*)d_in[25];
  const float* isu_W2= (const float*)d_in[26];
  const float* isu_b2= (const float*)d_in[27];

  float* out      = (float*)d_out;
  float* inv_node = out;                        // BA*FF   = 131072
  float* eqF      = out + 131072;               // BA*3    = 3072
  float* eqf      = out + 134144;               // BA*3*FF = 393216
  float* eqdr     = out + 527360;               // BA*3*FF = 393216

  // workspace layout (floats), total 10,196,992 floats = 40.8 MB
  float* w        = (float*)d_ws;
  float* msg_node = w;                          //   131,072
  float* esu_o    = w + 131072;                 //   131,072
  float* isu_o    = w + 262144;                 //   131,072
  float* scalg    = w + 393216;                 //   262,144 (EDG*4)
  float* eqdrT_A  = w + 655360;                 //   524,288 (BA*FF*4)
  float* eqdrT_B  = w + 1179648;                //   524,288
  unsigned short* wbf = (unsigned short*)(w + 1703936); // 208,896 us = 104,448 f
  unsigned short* H1  = (unsigned short*)(w + 1808384); // EDG*FF us = 4,194,304 f
  unsigned short* H2  = (unsigned short*)(w + 6002688); // EDG*FF us = 4,194,304 f

  hipMemsetAsync(out + 131072, 0, (size_t)(3072 + 2*393216)*sizeof(float), stream);
  hipMemsetAsync(eqdrT_A, 0, (size_t)524288*sizeof(float), stream);

  k_cvtw<<<817, 256, 0, stream>>>(eqf_W1, eqf_W2, eme_W1, eme_W2, me_W, wbf);
  k_init<<<BA*FF/256, 256, 0, stream>>>(z, emb, inv_node);

  for (int l=0; l<NLAY; ++l){
    size_t oW = (size_t)l*FF*FF, oB = (size_t)l*FF;
    const unsigned short* eqfW1b = wbf + 0*49152 + l*16384;
    const unsigned short* eqfW2b = wbf + 1*49152 + l*16384;
    const unsigned short* emeW1b = wbf + 2*49152 + l*16384;
    const unsigned short* emeW2b = wbf + 3*49152 + l*16384;
    const unsigned short* meWb   = wbf + 196608  + l*4096;
    float* dT_prev = (l & 1) ? eqdrT_B : eqdrT_A;
    float* dT_next = (l & 1) ? eqdrT_A : eqdrT_B;

    k_mlp_node3<<<dim3(BA/16, 3), 128, 0, stream>>>(inv_node,
        mn_W1+oW,  mn_b1+oB,  mn_W2+oW,  mn_b2+oB,  msg_node,
        esu_W1+oW, esu_b1+oB, esu_W2+oW, esu_b2+oB, esu_o,
        isu_W1+oW, isu_b1+oB, isu_W2+oW, isu_b2+oB, isu_o);
    k_edge1<<<BA/2, 256, 0, stream>>>(dist, dvec, maskp, nbrs, msg_node,
        meWb, me_b+oB, eqc_W+oB, eqfW1b, eqf_b1+oB, emeW1b,
        H1, H2, scalg, eqF);
    k_z<<<BA, 256, 0, stream>>>(H1, H2, eqfW2b, eqf_b2+oB, emeW2b,
        scalg, nbrs, dT_prev, dT_next, esu_o, isu_o,
        eqf, eqdr, inv_node);
  }
}